// Round 4
// baseline (643.909 us; speedup 1.0000x reference)
//
#include <hip/hip_runtime.h>
#include <math.h>
#include <stdint.h>

// R4 (on R3's fused 4-gate kernel, 448us @ 920 TF eff):
//  (a) both-sides LDS XOR swizzle on all BK=32 tiles: chunk c of row r stored at
//      c ^ ((r>>1)&3). Kills the 8-way ds_read_b128 conflict (3.15e7 cyc/dispatch
//      = 11.4% of CU-cycles). Staging keeps linear gl_lds dest; the SOURCE chunk
//      is inverse-permuted; reads apply the same XOR (rule #21, proven in R2).
//  (b) 3 pack kernels merged into 1 launch.
//  (c) workspace compacted (dead Gfo region removed).
// Sync structure untouched (proven 2-barrier/BK=32 dbuf, 2 blocks/CU).

#define DI static __device__ __forceinline__

typedef __bf16 bf16x8 __attribute__((ext_vector_type(8)));
typedef float f32x4 __attribute__((ext_vector_type(4)));
typedef float float4v __attribute__((ext_vector_type(4)));
typedef unsigned short u16;
typedef unsigned short u16x4 __attribute__((ext_vector_type(4)));

DI float b2f(u16 s) {
    unsigned u = ((unsigned)s) << 16;
    float f;
    __builtin_memcpy(&f, &u, 4);
    return f;
}
DI u16 f2b(float f) {
    unsigned x;
    __builtin_memcpy(&x, &f, 4);
    unsigned r = x + 0x7FFFu + ((x >> 16) & 1u);
    return (u16)(r >> 16);
}

// async global->LDS, 16B/lane; LDS dest = wave-uniform base + lane*16 (linear)
DI void gl_lds(const u16* g, u16* l) {
    __builtin_amdgcn_global_load_lds(
        (__attribute__((address_space(1))) void*)g,
        (__attribute__((address_space(3))) void*)l,
        16, 0, 0);
}

DI float fast_tanh(float x) {
    float xc = fminf(fmaxf(x, -15.f), 15.f);
    float e = __expf(2.0f * xc);
    return (e - 1.f) / (e + 1.f);
}

// ============ merged pack kernel ============
// blocks [0,8192): A rows; [8192,16384): W gate-rows; [16384,16896): Wp rows.
__global__ void pack_all(const float* __restrict__ inp, const float* __restrict__ hx,
                         const float* __restrict__ wx, const float* __restrict__ wh,
                         const float* __restrict__ wproj,
                         u16* __restrict__ Ahi, u16* __restrict__ Alo,
                         u16* __restrict__ Whi, u16* __restrict__ Wlo,
                         u16* __restrict__ Wp) {
    const int id = blockIdx.x;
    const int tid = threadIdx.x;
    if (id < 8192) {
        const int r = id;
        const int k = tid * 4;
        float4v v = (k < 1024) ? *(const float4v*)(inp + (size_t)r * 1024 + k)
                               : *(const float4v*)(hx + (size_t)r * 512 + (k - 1024));
        u16x4 h, l;
#pragma unroll
        for (int e = 0; e < 4; ++e) {
            h[e] = f2b(v[e]);
            l[e] = f2b(v[e] - b2f(h[e]));
        }
        *(u16x4*)(Ahi + (size_t)r * 1536 + k) = h;
        *(u16x4*)(Alo + (size_t)r * 1536 + k) = l;
    } else if (id < 16384) {
        const int g = id - 8192;
        const int k = tid * 4;
        float4v v = (k < 1024) ? *(const float4v*)(wx + (size_t)g * 1024 + k)
                               : *(const float4v*)(wh + (size_t)g * 512 + (k - 1024));
        u16x4 h, l;
#pragma unroll
        for (int e = 0; e < 4; ++e) {
            h[e] = f2b(v[e]);
            l[e] = f2b(v[e] - b2f(h[e]));
        }
        *(u16x4*)(Whi + (size_t)g * 1536 + k) = h;
        int lr = -1;
        if (g < 2048) lr = g;
        else if (g >= 4096 && g < 6144) lr = g - 2048;
        if (lr >= 0) *(u16x4*)(Wlo + (size_t)lr * 1536 + k) = l;
    } else {
        const int r = id - 16384;  // [0,512)
        for (int k = tid * 4; k < 2048; k += 1536) {
            float4v v = *(const float4v*)(wproj + (size_t)r * 2048 + k);
            u16x4 o;
#pragma unroll
            for (int e = 0; e < 4; ++e) o[e] = f2b(v[e]);
            *(u16x4*)(Wp + (size_t)r * 2048 + k) = o;
        }
    }
}

// ---- XCD swizzle (proven: FETCH 333-366 MB): id -> (bx in [0,32), by in [0,64))
DI void swizzle2048(int id, int& bx, int& by) {
    const int xcd = id & 7;
    const int j = id >> 3;
    bx = xcd * 4 + (j & 3);
    by = j >> 2;
}

// ============ fused 4-gate GEMM + LSTM cell (2-barrier structure + T2 swizzle) ====
// Per block: M=128 x h=64. f,o: 1 bf16 term; i,c: 3 split-bf16 terms.
// LDS tiles [rows][BK=32] with 16B-chunk swizzle: LDS[r][c] = SRC[r][c^((r>>1)&3)].
__global__ __launch_bounds__(256, 2) void gemm_gates_cell(
    const u16* __restrict__ Ahi, const u16* __restrict__ Alo,
    const u16* __restrict__ Whi, const u16* __restrict__ Wlo,
    const float* __restrict__ bxv, const float* __restrict__ bhv,
    const float* __restrict__ cx, float* __restrict__ ct, u16* __restrict__ U) {
    constexpr int K = 1536, BK = 32;
    constexpr int AB = 128 * BK;  // 4096 elems per A buffer
    constexpr int WB = 64 * BK;   // 2048 elems per W buffer
    __shared__ u16 sAh[2 * AB], sAl[2 * AB];
    __shared__ u16 sWf[2 * WB], sWo[2 * WB];
    __shared__ u16 sWih[2 * WB], sWil[2 * WB], sWch[2 * WB], sWcl[2 * WB];
    // total = 81920 B -> exactly 2 blocks/CU

    const int tid = threadIdx.x, wave = tid >> 6, lane = tid & 63;
    int bxi, byi;
    swizzle2048(blockIdx.x, bxi, byi);
    const size_t tileM = (size_t)byi * 128;
    const size_t h0 = (size_t)bxi * 64;
    const int waveM = (wave >> 1) * 64;
    const int waveH = (wave & 1) * 32;

    // staging: lane l fills LDS (row=l>>2, chunk=l&3) of its 16-row slab ->
    // source chunk = (l&3) ^ f(row), f(r)=(r>>1)&3 -> (lane>>3)&3
    const int srow = lane >> 2;
    const int scol = ((lane & 3) ^ ((lane >> 3) & 3)) * 8;
    const size_t wr = (size_t)(wave * 16 + srow);
    const u16* gAh = Ahi + (tileM + wr) * K + scol;
    const u16* gAl = Alo + (tileM + wr) * K + scol;
    // gate-row bases in Whi: i @ h, f @ 2048+h, c @ 4096+h, o @ 6144+h
    const u16* gWih = Whi + (h0 + wr) * K + scol;
    const u16* gWf  = Whi + (2048 + h0 + wr) * K + scol;
    const u16* gWch = Whi + (4096 + h0 + wr) * K + scol;
    const u16* gWo  = Whi + (6144 + h0 + wr) * K + scol;
    const u16* gWil = Wlo + (h0 + wr) * K + scol;
    const u16* gWcl = Wlo + (2048 + h0 + wr) * K + scol;
    const int lA0 = (wave * 16) * BK;
    const int lA1 = (wave * 16 + 64) * BK;
    const int lW0 = (wave * 16) * BK;

    f32x4 aF[4][2] = {}, aO[4][2] = {}, aI[4][2] = {}, aC[4][2] = {};
    const int arow = waveM + (lane & 15);
    const int wrow = waveH + (lane & 15);
    // read: logical K-chunk (lane>>4) lives at chunk (lane>>4) ^ f(row);
    // f(row) = ((lane&15)>>1)&3 = (lane>>1)&3 for all frag rows (offsets = 0 mod 16)
    const int kq = ((lane >> 4) ^ ((lane >> 1) & 3)) * 8;

#define STAGE_G(b, k0)                                           \
    do {                                                         \
        gl_lds(gAh + (k0), &sAh[(b)*AB + lA0]);                  \
        gl_lds(gAh + (size_t)64 * K + (k0), &sAh[(b)*AB + lA1]); \
        gl_lds(gAl + (k0), &sAl[(b)*AB + lA0]);                  \
        gl_lds(gAl + (size_t)64 * K + (k0), &sAl[(b)*AB + lA1]); \
        gl_lds(gWf + (k0), &sWf[(b)*WB + lW0]);                  \
        gl_lds(gWo + (k0), &sWo[(b)*WB + lW0]);                  \
        gl_lds(gWih + (k0), &sWih[(b)*WB + lW0]);                \
        gl_lds(gWil + (k0), &sWil[(b)*WB + lW0]);                \
        gl_lds(gWch + (k0), &sWch[(b)*WB + lW0]);                \
        gl_lds(gWcl + (k0), &sWcl[(b)*WB + lW0]);                \
    } while (0)

#define COMPUTE_G(b)                                                              \
    do {                                                                          \
        bf16x8 ah[4], al[4];                                                      \
        _Pragma("unroll") for (int i = 0; i < 4; ++i) {                           \
            ah[i] = *(const bf16x8*)&sAh[(b)*AB + (arow + i * 16) * BK + kq];     \
            al[i] = *(const bf16x8*)&sAl[(b)*AB + (arow + i * 16) * BK + kq];     \
        }                                                                         \
        { /* f gate: 1 term */                                                    \
            bf16x8 w[2];                                                          \
            _Pragma("unroll") for (int j = 0; j < 2; ++j)                         \
                w[j] = *(const bf16x8*)&sWf[(b)*WB + (wrow + j * 16) * BK + kq];  \
            _Pragma("unroll") for (int i = 0; i < 4; ++i)                         \
                _Pragma("unroll") for (int j = 0; j < 2; ++j)                     \
                    aF[i][j] = __builtin_amdgcn_mfma_f32_16x16x32_bf16(           \
                        ah[i], w[j], aF[i][j], 0, 0, 0);                          \
        }                                                                         \
        { /* o gate: 1 term */                                                    \
            bf16x8 w[2];                                                          \
            _Pragma("unroll") for (int j = 0; j < 2; ++j)                         \
                w[j] = *(const bf16x8*)&sWo[(b)*WB + (wrow + j * 16) * BK + kq];  \
            _Pragma("unroll") for (int i = 0; i < 4; ++i)                         \
                _Pragma("unroll") for (int j = 0; j < 2; ++j)                     \
                    aO[i][j] = __builtin_amdgcn_mfma_f32_16x16x32_bf16(           \
                        ah[i], w[j], aO[i][j], 0, 0, 0);                          \
        }                                                                         \
        { /* i gate: 3 terms */                                                   \
            bf16x8 wh[2], wl[2];                                                  \
            _Pragma("unroll") for (int j = 0; j < 2; ++j) {                       \
                wh[j] = *(const bf16x8*)&sWih[(b)*WB + (wrow + j * 16) * BK + kq];\
                wl[j] = *(const bf16x8*)&sWil[(b)*WB + (wrow + j * 16) * BK + kq];\
            }                                                                     \
            _Pragma("unroll") for (int i = 0; i < 4; ++i)                         \
                _Pragma("unroll") for (int j = 0; j < 2; ++j) {                   \
                    aI[i][j] = __builtin_amdgcn_mfma_f32_16x16x32_bf16(           \
                        ah[i], wh[j], aI[i][j], 0, 0, 0);                         \
                    aI[i][j] = __builtin_amdgcn_mfma_f32_16x16x32_bf16(           \
                        al[i], wh[j], aI[i][j], 0, 0, 0);                         \
                    aI[i][j] = __builtin_amdgcn_mfma_f32_16x16x32_bf16(           \
                        ah[i], wl[j], aI[i][j], 0, 0, 0);                         \
                }                                                                 \
        }                                                                         \
        { /* c gate: 3 terms */                                                   \
            bf16x8 wh[2], wl[2];                                                  \
            _Pragma("unroll") for (int j = 0; j < 2; ++j) {                       \
                wh[j] = *(const bf16x8*)&sWch[(b)*WB + (wrow + j * 16) * BK + kq];\
                wl[j] = *(const bf16x8*)&sWcl[(b)*WB + (wrow + j * 16) * BK + kq];\
            }                                                                     \
            _Pragma("unroll") for (int i = 0; i < 4; ++i)                         \
                _Pragma("unroll") for (int j = 0; j < 2; ++j) {                   \
                    aC[i][j] = __builtin_amdgcn_mfma_f32_16x16x32_bf16(           \
                        ah[i], wh[j], aC[i][j], 0, 0, 0);                         \
                    aC[i][j] = __builtin_amdgcn_mfma_f32_16x16x32_bf16(           \
                        al[i], wh[j], aC[i][j], 0, 0, 0);                         \
                    aC[i][j] = __builtin_amdgcn_mfma_f32_16x16x32_bf16(           \
                        ah[i], wl[j], aC[i][j], 0, 0, 0);                         \
                }                                                                 \
        }                                                                         \
    } while (0)

    STAGE_G(0, 0);
    __syncthreads();
    for (int k0 = 0; k0 < K; k0 += 2 * BK) {
        STAGE_G(1, k0 + BK);
        COMPUTE_G(0);
        __syncthreads();
        if (k0 + 2 * BK < K) STAGE_G(0, k0 + 2 * BK);
        COMPUTE_G(1);
        __syncthreads();
    }
#undef STAGE_G
#undef COMPUTE_G

    // ---- fully in-register LSTM cell epilogue ----
    const int rq = (lane >> 4) * 4;
#pragma unroll
    for (int j = 0; j < 2; ++j) {
        const size_t h = h0 + waveH + j * 16 + (lane & 15);
        const float bi = bxv[h] + bhv[h];
        const float bf = bxv[2048 + h] + bhv[2048 + h];
        const float bc = bxv[4096 + h] + bhv[4096 + h];
        const float bo = bxv[6144 + h] + bhv[6144 + h];
#pragma unroll
        for (int i = 0; i < 4; ++i) {
            const size_t m0 = tileM + waveM + i * 16 + rq;
#pragma unroll
            for (int v = 0; v < 4; ++v) {
                const size_t m = m0 + v;
                const float fv = aF[i][j][v] + bf;
                const float ov = aO[i][j][v] + bo;
                const float iv = aI[i][j][v] + bi;
                const float cv = aC[i][j][v] + bc;
                const float c_ = fv * cx[m * 2048 + h] + iv * cv;
                ct[m * 2048 + h] = c_;
                U[m * 2048 + h] = f2b(ov * fast_tanh(c_));
            }
        }
    }
}

// ============ proj: ht[B,512] = U[B,2048] * Wp[512,2048]^T (same swizzle) ============
__global__ __launch_bounds__(256, 2) void gemm_proj(const u16* __restrict__ A,
                                                    const u16* __restrict__ W,
                                                    float* __restrict__ out) {
    constexpr int K = 2048, BK = 32;
    constexpr int AB = 128 * BK;
    constexpr int WB = 64 * BK;
    __shared__ u16 As[2 * AB];
    __shared__ u16 Ws[2 * WB];

    const int tid = threadIdx.x, wave = tid >> 6, lane = tid & 63;
    const size_t tileM = (size_t)blockIdx.y * 128;
    const size_t tileN = (size_t)blockIdx.x * 64;
    const int waveM = (wave >> 1) * 64;
    const int waveN = (wave & 1) * 32;

    const int srow = lane >> 2;
    const int scol = ((lane & 3) ^ ((lane >> 3) & 3)) * 8;
    const u16* Ag = A + (tileM + (size_t)(wave * 16 + srow)) * K + scol;
    const u16* Wg = W + (tileN + (size_t)(wave * 16 + srow)) * K + scol;
    const int lA0 = (wave * 16) * BK;
    const int lA1 = (wave * 16 + 64) * BK;

    f32x4 acc[4][2] = {};
    const int arow = waveM + (lane & 15);
    const int wrow = waveN + (lane & 15);
    const int kq = ((lane >> 4) ^ ((lane >> 1) & 3)) * 8;

#define STAGE_PR(b, k0)                                        \
    do {                                                       \
        gl_lds(Ag + (k0), &As[(b)*AB + lA0]);                  \
        gl_lds(Ag + (size_t)64 * K + (k0), &As[(b)*AB + lA1]); \
        gl_lds(Wg + (k0), &Ws[(b)*WB + lA0]);                  \
    } while (0)

#define COMPUTE_PR(b)                                                          \
    do {                                                                       \
        bf16x8 af[4], wf[2];                                                   \
        _Pragma("unroll") for (int i = 0; i < 4; ++i)                          \
            af[i] = *(const bf16x8*)&As[(b)*AB + (arow + i * 16) * BK + kq];   \
        _Pragma("unroll") for (int j = 0; j < 2; ++j)                          \
            wf[j] = *(const bf16x8*)&Ws[(b)*WB + (wrow + j * 16) * BK + kq];   \
        _Pragma("unroll") for (int i = 0; i < 4; ++i)                          \
            _Pragma("unroll") for (int j = 0; j < 2; ++j)                      \
                acc[i][j] = __builtin_amdgcn_mfma_f32_16x16x32_bf16(           \
                    af[i], wf[j], acc[i][j], 0, 0, 0);                         \
    } while (0)

    STAGE_PR(0, 0);
    __syncthreads();
    for (int k0 = 0; k0 < K; k0 += 2 * BK) {
        STAGE_PR(1, k0 + BK);
        COMPUTE_PR(0);
        __syncthreads();
        if (k0 + 2 * BK < K) STAGE_PR(0, k0 + 2 * BK);
        COMPUTE_PR(1);
        __syncthreads();
    }
#undef STAGE_PR
#undef COMPUTE_PR

    const int rq = (lane >> 4) * 4;
#pragma unroll
    for (int i = 0; i < 4; ++i) {
        const size_t rbase = tileM + waveM + i * 16 + rq;
#pragma unroll
        for (int j = 0; j < 2; ++j) {
            const size_t n = tileN + waveN + (lane & 15) + j * 16;
#pragma unroll
            for (int v = 0; v < 4; ++v)
                out[(rbase + v) * 512 + n] = acc[i][j][v];
        }
    }
}

// ============ launch ============
extern "C" void kernel_launch(void* const* d_in, const int* in_sizes, int n_in,
                              void* d_out, int out_size, void* d_ws, size_t ws_size,
                              hipStream_t stream) {
    const float* input  = (const float*)d_in[0];
    const float* hx     = (const float*)d_in[1];
    const float* cx     = (const float*)d_in[2];
    const float* w_x    = (const float*)d_in[3];
    const float* b_x    = (const float*)d_in[4];
    const float* w_h    = (const float*)d_in[5];
    const float* b_h    = (const float*)d_in[6];
    const float* w_proj = (const float*)d_in[7];

    constexpr int H = 2048, P = 512, B = 8192;

    char* ws = (char*)d_ws;
    u16* Ahi = (u16*)(ws);                 // [8192,1536] 25,165,824
    u16* Alo = (u16*)(ws + 25165824);      // [8192,1536] 25,165,824
    u16* Whi = (u16*)(ws + 50331648);      // [8192,1536] 25,165,824
    u16* Wlo = (u16*)(ws + 75497472);      // [4096,1536] 12,582,912
    u16* U   = (u16*)(ws + 88080384);      // [8192,2048] 33,554,432
    u16* Wp  = (u16*)(ws + 121634816);     // [512,2048]   2,097,152

    float* ht = (float*)d_out;
    float* ct = (float*)d_out + (size_t)B * P;

    pack_all<<<16896, 384, 0, stream>>>(input, hx, w_x, w_h, w_proj,
                                        Ahi, Alo, Whi, Wlo, Wp);

    gemm_gates_cell<<<2048, 256, 0, stream>>>(Ahi, Alo, Whi, Wlo, b_x, b_h,
                                              cx, ct, U);
    gemm_proj<<<dim3(8, 64), 256, 0, stream>>>(U, Wp, ht);
}